// Round 10
// baseline (261.984 us; speedup 1.0000x reference)
//
#include <hip/hip_runtime.h>

#define BB   8
#define CIN  96
#define DIN  192
#define HH   64
#define WW   64
#define LL   4096
#define KK   4
#define COUT 96
#define SS   128  // scan segments
#define LC   32   // segment length = LL/SS

#define LOG2E 1.4426950408889634f
#define LN2   0.6931471805599453f

__device__ __forceinline__ float exp2fast(float x) { return __builtin_amdgcn_exp2f(x); }
__device__ __forceinline__ float log2fast(float x) { return __builtin_amdgcn_logf(x); }
__device__ __forceinline__ float sigf(float x) { return 1.0f / (1.0f + __expf(-x)); }
__device__ __forceinline__ int trp(int p) { return ((p & 63) << 6) | (p >> 6); }
__device__ __forceinline__ int pix_of(int k, int l) {
  if (k == 0) return l;
  if (k == 1) return trp(l);
  if (k == 2) return LL - 1 - l;
  return trp(LL - 1 - l);
}

// ---------------------------------------------------------------------------
// Per-pixel GEMM: out[b,o,p] = sum_c in[b,c,p] * W[o,c]
// ---------------------------------------------------------------------------
template <int C>
__global__ __launch_bounds__(256) void gemm_pix_k(const float* __restrict__ in,
                                                  const float* __restrict__ W,
                                                  float* __restrict__ out, int O) {
  __shared__ float sW[C * 8];
  const int tid = threadIdx.x;
  const int b  = blockIdx.z;
  const int o0 = blockIdx.y * 8;
  const int p0 = blockIdx.x * 1024;
  for (int idx = tid; idx < C * 8; idx += 256) {
    int c = idx >> 3, j = idx & 7;
    sW[idx] = W[(o0 + j) * C + c];
  }
  __syncthreads();
  float acc[4][8];
#pragma unroll
  for (int jp = 0; jp < 4; ++jp)
#pragma unroll
    for (int j = 0; j < 8; ++j) acc[jp][j] = 0.0f;
  const float* inb = in + (size_t)b * C * LL + p0 + tid;
#pragma unroll 2
  for (int c = 0; c < C; ++c) {
    float xv[4];
#pragma unroll
    for (int jp = 0; jp < 4; ++jp) xv[jp] = inb[(size_t)c * LL + jp * 256];
    const float4 w0 = *(const float4*)&sW[c * 8];
    const float4 w1 = *(const float4*)&sW[c * 8 + 4];
#pragma unroll
    for (int jp = 0; jp < 4; ++jp) {
      acc[jp][0] = fmaf(xv[jp], w0.x, acc[jp][0]);
      acc[jp][1] = fmaf(xv[jp], w0.y, acc[jp][1]);
      acc[jp][2] = fmaf(xv[jp], w0.z, acc[jp][2]);
      acc[jp][3] = fmaf(xv[jp], w0.w, acc[jp][3]);
      acc[jp][4] = fmaf(xv[jp], w1.x, acc[jp][4]);
      acc[jp][5] = fmaf(xv[jp], w1.y, acc[jp][5]);
      acc[jp][6] = fmaf(xv[jp], w1.z, acc[jp][6]);
      acc[jp][7] = fmaf(xv[jp], w1.w, acc[jp][7]);
    }
  }
  float* ob = out + (size_t)b * O * LL + p0 + tid;
#pragma unroll
  for (int j = 0; j < 8; ++j)
#pragma unroll
    for (int jp = 0; jp < 4; ++jp) ob[(size_t)(o0 + j) * LL + jp * 256] = acc[jp][j];
}

// ---------------------------------------------------------------------------
// PriorToWeights MLP -> Wg[B,4,L].  Block 0 also transposes x_proj_weight
// into xpwT[k][dd][8] for convproj_k (consumer launches later; no race).
// ---------------------------------------------------------------------------
__global__ __launch_bounds__(256) void p2w_k(const float* __restrict__ prior,
                                             const float* __restrict__ alpha,
                                             const float* __restrict__ w1,
                                             const float* __restrict__ b1,
                                             const float* __restrict__ bnw,
                                             const float* __restrict__ bnb,
                                             const float* __restrict__ bnm,
                                             const float* __restrict__ bnv,
                                             const float* __restrict__ w2,
                                             const float* __restrict__ b2,
                                             const float* __restrict__ xpw,
                                             float* __restrict__ xpwT,
                                             float* __restrict__ Wg) {
  if (blockIdx.x == 0) {
    for (int idx = threadIdx.x; idx < KK * DIN * 8; idx += 256) {
      int kk = idx / (DIN * 8);
      int rem = idx % (DIN * 8);
      int dd = rem >> 3, c = rem & 7;
      xpwT[idx] = xpw[(kk * 8 + c) * DIN + dd];
    }
  }
  int idx = blockIdx.x * 256 + threadIdx.x;
  int p = idx & (LL - 1);
  int b = idx >> 12;
  float pr[4];
#pragma unroll
  for (int c = 0; c < 4; ++c) pr[c] = prior[((size_t)b * 4 + c) * LL + p];
  float s = sigf(alpha[0]);
  float g2[4];
#pragma unroll
  for (int j = 0; j < 4; ++j) g2[j] = b2[j];
  for (int o = 0; o < 32; ++o) {
    float g = b1[o];
#pragma unroll
    for (int c = 0; c < 4; ++c) g = fmaf(pr[c], w1[o * 4 + c], g);
    g = (g - bnm[o]) * rsqrtf(bnv[o] + 1e-5f) * bnw[o] + bnb[o];
    g = fmaxf(g, 0.0f);
#pragma unroll
    for (int j = 0; j < 4; ++j) g2[j] = fmaf(g, w2[j * 32 + o], g2[j]);
  }
#pragma unroll
  for (int j = 0; j < 4; ++j)
    Wg[((size_t)b * 4 + j) * LL + p] = 1.0f + s * (sigf(g2[j]) - 1.0f);
}

// ---------------------------------------------------------------------------
// FUSED conv+proj v3: 32-pixel tiles -> 1024 blocks (was grid-limited at 512).
// LDS 25.3 KB tile [192][33]; proj thread = (px,k,half), 4 acc, float4 weights.
// ---------------------------------------------------------------------------
__global__ __launch_bounds__(256) void convproj_k(const float* __restrict__ xz,
                                                  const float* __restrict__ cw,
                                                  const float* __restrict__ cb,
                                                  const float* __restrict__ xpwT,
                                                  float* __restrict__ xcT,
                                                  float* __restrict__ projS) {
  __shared__ float sX[DIN * 33];  // 25.3 KB
  const int tid = threadIdx.x;
  const int b = blockIdx.y;
  const int tile = blockIdx.x;     // 0..127
  const int h  = tile >> 1;
  const int w0 = (tile & 1) << 5;  // 0 or 32
  // conv + bias + SiLU for all 192 channels x 32 pixels into sX[dd][px]
  for (int idx = tid; idx < DIN * 32; idx += 256) {
    int dd = idx >> 5, pxx = idx & 31;
    int w = w0 + pxx;
    const float* xp = xz + ((size_t)b * 384 + dd) * LL + h * 64 + w;
    const float* wp = cw + dd * 9;
    float s = cb[dd];
#pragma unroll
    for (int dh = -1; dh <= 1; ++dh) {
      int hh = h + dh;
      if (hh < 0 || hh >= HH) continue;
      const float* row = xp + dh * 64;
      float c0 = wp[(dh + 1) * 3], c1 = wp[(dh + 1) * 3 + 1], c2 = wp[(dh + 1) * 3 + 2];
      if (w > 0)  s = fmaf(row[-1], c0, s);
      s = fmaf(row[0], c1, s);
      if (w < 63) s = fmaf(row[1], c2, s);
    }
    sX[dd * 33 + pxx] = s * sigf(s);
  }
  __syncthreads();
  // transposed write xcT[b][p][dd] (coalesced over dd)
  for (int idx = tid; idx < 32 * DIN; idx += 256) {
    int pp = idx / DIN, dd = idx % DIN;
    xcT[((size_t)b * LL + h * 64 + w0 + pp) * DIN + dd] = sX[dd * 33 + pp];
  }
  // x_proj: thread = (px, k, hf); 4 outputs each; dd order 0..191 preserved
  const int px = tid & 31;
  const int k  = (tid >> 5) & 3;
  const int hf = tid >> 7;
  const float* wp = xpwT + (size_t)k * (DIN * 8) + hf * 4;
  float a0 = 0.0f, a1 = 0.0f, a2 = 0.0f, a3 = 0.0f;
  for (int dd = 0; dd < DIN; ++dd) {
    float xv = sX[dd * 33 + px];
    const float4 w4 = *(const float4*)(wp + dd * 8);
    a0 = fmaf(xv, w4.x, a0);
    a1 = fmaf(xv, w4.y, a1);
    a2 = fmaf(xv, w4.z, a2);
    a3 = fmaf(xv, w4.w, a3);
  }
  const int p = h * 64 + w0 + px;
  int l;
  if (k == 0) l = p;
  else if (k == 1) l = trp(p);
  else if (k == 2) l = LL - 1 - p;
  else l = LL - 1 - trp(p);
  float* pb = projS + (((size_t)b * KK + k) * LL + l) * 8 + hf * 4;
  *(float4*)pb = make_float4(a0, a1, a2, a3);
}

// ---------------------------------------------------------------------------
// Scan pass 1: per-segment carries (P,H). thread = d, block = (seg,k,b).
// ---------------------------------------------------------------------------
__global__ __launch_bounds__(192) void scan_part_k(const float* __restrict__ xcT,
                                                   const float* __restrict__ projS,
                                                   const float* __restrict__ dtw,
                                                   const float* __restrict__ dtb,
                                                   const float* __restrict__ A_logs,
                                                   float* __restrict__ carrP,
                                                   float* __restrict__ carrH) {
  const int s = blockIdx.x, k = blockIdx.y, b = blockIdx.z;
  const int d = threadIdx.x;
  const int kd = k * DIN + d;
  float wr[6];
#pragma unroll
  for (int r = 0; r < 6; ++r) wr[r] = dtw[kd * 6 + r];
  const float bias = dtb[kd];
  const float Aa = -__expf(A_logs[kd]);
  const int l0 = s * LC;
  const int p0 = pix_of(k, l0);
  const int dp = pix_of(k, l0 + 1) - p0;
  const float* xp = xcT + ((size_t)b * LL + p0) * DIN + d;
  const long xstep = (long)dp * DIN;
  const float* pr = projS + (((size_t)b * KK + k) * LL + l0) * 8;
  float P = 1.0f, h = 0.0f;
#pragma unroll 4
  for (int j = 0; j < LC; ++j) {
    float4 q0 = *(const float4*)pr;
    float4 q1 = *(const float4*)(pr + 4);
    pr += 8;
    float xv = *xp;
    xp += xstep;
    float dtr = bias;
    dtr = fmaf(q0.x, wr[0], dtr);
    dtr = fmaf(q0.y, wr[1], dtr);
    dtr = fmaf(q0.z, wr[2], dtr);
    dtr = fmaf(q0.w, wr[3], dtr);
    dtr = fmaf(q1.x, wr[4], dtr);
    dtr = fmaf(q1.y, wr[5], dtr);
    float e = exp2fast(fminf(dtr, 80.0f) * LOG2E);
    float u = log2fast(1.0f + e);      // softplus in base-2
    float a = exp2fast(u * Aa);        // exp(dt*Aa) = 2^(u*Aa)
    float dt = u * LN2;
    h = fmaf(a, h, dt * q1.z * xv);
    P *= a;
  }
  size_t o = ((size_t)((b * KK + k) * SS + s)) * DIN + d;
  carrP[o] = P;
  carrH[o] = h;
}

// ---------------------------------------------------------------------------
// Scan pass 2: serial combine of SS carries -> per-segment initial state h0
// ---------------------------------------------------------------------------
__global__ __launch_bounds__(192) void scan_fix_k(const float* __restrict__ carrP,
                                                  const float* __restrict__ carrH,
                                                  float* __restrict__ h0) {
  const int k = blockIdx.x, b = blockIdx.y, d = threadIdx.x;
  size_t base = ((size_t)(b * KK + k)) * SS * DIN + d;
  float h = 0.0f;
#pragma unroll 4
  for (int s = 0; s < SS; ++s) {
    h0[base + (size_t)s * DIN] = h;
    h = fmaf(carrP[base + (size_t)s * DIN], h, carrH[base + (size_t)s * DIN]);
  }
}

// ---------------------------------------------------------------------------
// Scan pass 3: apply + gate + paired-direction merge via 24 KB LDS.
// pair kp=0: k=0 + k=2 -> ymT (overlaid on xz x_ssm half, b-stride 384*LL)
// pair kp=1: k=1 + k=3 -> ymT2[b,t,d]
// ---------------------------------------------------------------------------
__global__ __launch_bounds__(192) void scan_apply_k(const float* __restrict__ xcT,
                                                    const float* __restrict__ projS,
                                                    const float* __restrict__ Wg,
                                                    const float* __restrict__ h0,
                                                    const float* __restrict__ dtw,
                                                    const float* __restrict__ dtb,
                                                    const float* __restrict__ A_logs,
                                                    const float* __restrict__ Ds,
                                                    float* __restrict__ ymT,
                                                    float* __restrict__ ymT2) {
  const int s = blockIdx.x, kp = blockIdx.y, b = blockIdx.z;
  const int d = threadIdx.x;
  __shared__ float sAcc[LC * DIN];  // 24 KB, column d thread-private
  // ---- direction A = kp, segment s ----
  {
    const int k = kp, kd = k * DIN + d;
    float wr[6];
#pragma unroll
    for (int r = 0; r < 6; ++r) wr[r] = dtw[kd * 6 + r];
    const float bias = dtb[kd];
    const float Aa = -__expf(A_logs[kd]);
    const float Dv = Ds[kd];
    const int l0 = s * LC;
    const int p0 = pix_of(k, l0);
    const int dp = pix_of(k, l0 + 1) - p0;
    const float* xp = xcT + ((size_t)b * LL + p0) * DIN + d;
    const long xstep = (long)dp * DIN;
    const float* pr = projS + (((size_t)b * KK + k) * LL + l0) * 8;
    const float* wg = Wg + ((size_t)b * KK + k) * LL + l0;
    float h = h0[((size_t)((b * KK + k) * SS + s)) * DIN + d];
#pragma unroll 4
    for (int j = 0; j < LC; ++j) {
      float4 q0 = *(const float4*)pr;
      float4 q1 = *(const float4*)(pr + 4);
      pr += 8;
      float xv = *xp;
      xp += xstep;
      float dtr = bias;
      dtr = fmaf(q0.x, wr[0], dtr);
      dtr = fmaf(q0.y, wr[1], dtr);
      dtr = fmaf(q0.z, wr[2], dtr);
      dtr = fmaf(q0.w, wr[3], dtr);
      dtr = fmaf(q1.x, wr[4], dtr);
      dtr = fmaf(q1.y, wr[5], dtr);
      float e = exp2fast(fminf(dtr, 80.0f) * LOG2E);
      float u = log2fast(1.0f + e);
      float a = exp2fast(u * Aa);
      float dt = u * LN2;
      h = fmaf(a, h, dt * q1.z * xv);
      sAcc[j * DIN + d] = fmaf(h, q1.w, Dv * xv) * wg[j];
    }
  }
  // ---- direction B = kp+2, segment SS-1-s (same pixels, reversed) ----
  {
    const int k = kp + 2, kd = k * DIN + d;
    const int s2 = SS - 1 - s;
    float wr[6];
#pragma unroll
    for (int r = 0; r < 6; ++r) wr[r] = dtw[kd * 6 + r];
    const float bias = dtb[kd];
    const float Aa = -__expf(A_logs[kd]);
    const float Dv = Ds[kd];
    const int l0 = s2 * LC;
    const int p0 = pix_of(k, l0);
    const int dp = pix_of(k, l0 + 1) - p0;
    const float* xp = xcT + ((size_t)b * LL + p0) * DIN + d;
    const long xstep = (long)dp * DIN;
    const float* pr = projS + (((size_t)b * KK + k) * LL + l0) * 8;
    const float* wg = Wg + ((size_t)b * KK + k) * LL + l0;
    float h = h0[((size_t)((b * KK + k) * SS + s2)) * DIN + d];
#pragma unroll 4
    for (int j = 0; j < LC; ++j) {
      float4 q0 = *(const float4*)pr;
      float4 q1 = *(const float4*)(pr + 4);
      pr += 8;
      float xv = *xp;
      xp += xstep;
      float dtr = bias;
      dtr = fmaf(q0.x, wr[0], dtr);
      dtr = fmaf(q0.y, wr[1], dtr);
      dtr = fmaf(q0.z, wr[2], dtr);
      dtr = fmaf(q0.w, wr[3], dtr);
      dtr = fmaf(q1.x, wr[4], dtr);
      dtr = fmaf(q1.y, wr[5], dtr);
      float e = exp2fast(fminf(dtr, 80.0f) * LOG2E);
      float u = log2fast(1.0f + e);
      float a = exp2fast(u * Aa);
      float dt = u * LN2;
      h = fmaf(a, h, dt * q1.z * xv);
      float y = fmaf(h, q1.w, Dv * xv) * wg[j];
      sAcc[(LC - 1 - j) * DIN + d] += y;  // same thread-column: no race
    }
  }
  // flush (no sync needed: column d thread-private)
  float* dst;
  if (kp == 0)
    dst = ymT + (size_t)b * (384 * (size_t)LL) + (size_t)(s * LC) * DIN + d;  // xz overlay
  else
    dst = ymT2 + ((size_t)b * LL + s * LC) * DIN + d;
#pragma unroll 4
  for (int j = 0; j < LC; ++j) dst[(size_t)j * DIN] = sAcc[j * DIN + d];
}

// ---------------------------------------------------------------------------
// LayerNorm(channel) * silu(z): reads ymT(overlay)[p,:] + ymT2[tr(p),:], writes u
// ---------------------------------------------------------------------------
__global__ __launch_bounds__(256) void ln_silu_k(const float* __restrict__ ymT,
                                                 const float* __restrict__ ymT2,
                                                 const float* __restrict__ xz,
                                                 const float* __restrict__ gamma,
                                                 const float* __restrict__ beta,
                                                 float* __restrict__ u) {
  const int b = blockIdx.y;
  const int h = blockIdx.x;
  const int p0 = h * 64;
  __shared__ float sY[64 * 193];
  __shared__ float sS[4][64], sQ[4][64];
  const int tid = threadIdx.x;
  const float* ymb = ymT + (size_t)b * (384 * (size_t)LL);  // xz overlay, b-stride 384*L
  for (int idx = tid; idx < 64 * DIN; idx += 256) {
    int pp = idx / DIN, dd = idx % DIN;
    float v = ymb[(size_t)(p0 + pp) * DIN + dd] +
              ymT2[((size_t)b * LL + pp * 64 + h) * DIN + dd];
    sY[pp * 193 + dd] = v;
  }
  __syncthreads();
  const int px = tid & 63, g = tid >> 6;
  float sum = 0.0f, ss = 0.0f;
  for (int dd = g * 48; dd < g * 48 + 48; ++dd) {
    float v = sY[px * 193 + dd];
    sum += v;
    ss = fmaf(v, v, ss);
  }
  sS[g][px] = sum;
  sQ[g][px] = ss;
  __syncthreads();
  sum = sS[0][px] + sS[1][px] + sS[2][px] + sS[3][px];
  ss  = sQ[0][px] + sQ[1][px] + sQ[2][px] + sQ[3][px];
  const float mu = sum * (1.0f / DIN);
  float var = ss * (1.0f / DIN) - mu * mu;
  const float rstd = rsqrtf(fmaxf(var, 0.0f) + 1e-5f);
  const float* zb = xz + ((size_t)b * 384 + DIN) * LL + p0 + px;
  float* ub = u + (size_t)b * DIN * LL + p0 + px;
  for (int dd = g * 48; dd < g * 48 + 48; ++dd) {
    float v = sY[px * 193 + dd];
    float z = zb[(size_t)dd * LL];
    float tn = fmaf((v - mu) * rstd, gamma[dd], beta[dd]);
    ub[(size_t)dd * LL] = tn * (z * sigf(z));
  }
}

// ---------------------------------------------------------------------------
extern "C" void kernel_launch(void* const* d_in, const int* in_sizes, int n_in,
                              void* d_out, int out_size, void* d_ws, size_t ws_size,
                              hipStream_t stream) {
  const float* x      = (const float*)d_in[0];
  const float* prior  = (const float*)d_in[1];
  const float* alpha  = (const float*)d_in[2];
  const float* ipw    = (const float*)d_in[3];
  const float* cw     = (const float*)d_in[4];
  const float* cb     = (const float*)d_in[5];
  const float* xpw    = (const float*)d_in[6];
  const float* dtw    = (const float*)d_in[7];
  const float* dtb    = (const float*)d_in[8];
  const float* A_logs = (const float*)d_in[9];
  const float* Ds     = (const float*)d_in[10];
  const float* onw    = (const float*)d_in[11];
  const float* onb    = (const float*)d_in[12];
  const float* opw    = (const float*)d_in[13];
  const float* w1     = (const float*)d_in[14];
  const float* b1     = (const float*)d_in[15];
  const float* bnw    = (const float*)d_in[16];
  const float* bnb    = (const float*)d_in[17];
  const float* bnm    = (const float*)d_in[18];
  const float* bnv    = (const float*)d_in[19];
  const float* w2     = (const float*)d_in[20];
  const float* b2     = (const float*)d_in[21];
  float* out = (float*)d_out;

  char* ws = (char*)d_ws;
  // Footprint ends at 114,843,648 B (< 135,266,304 proven in R2).
  float* xz    = (float*)(ws);              // [B,384,L]     50.3 MB
  float* xcT   = (float*)(ws + 50331648);   // [B,L,192]     25.2 MB (-> u after apply)
  float* ymT2  = (float*)(ws + 75497472);   // [B,L,192]     25.2 MB
  float* projS = (float*)(ws + 100663296);  // [B,K,L,8]      4.2 MB (scan order)
  float* Wgb   = (float*)(ws + 104857600);  // [B,4,L]        0.5 MB
  float* carrP = (float*)(ws + 105381888);  // [B,K,SS,192]   3.0 MB
  float* carrH = (float*)(ws + 108527616);  // [B,K,SS,192]   3.0 MB
  float* h0b   = (float*)(ws + 111673344);  // [B,K,SS,192]   3.0 MB
  float* xpwT  = (float*)(ws + 114819072);  // [K,DIN,8]      24.6 KB (ends 114843648)
  float* ymT   = xz;   // overlay: x_ssm half of xz (dead after convproj), b-stride 384*L
  float* u     = xcT;  // xcT dead after scan_apply_k

  // 1) in_proj GEMM: [B,96,L] -> [B,384,L]
  gemm_pix_k<CIN><<<dim3(LL / 1024, 384 / 8, BB), 256, 0, stream>>>(x, ipw, xz, 384);
  // 2) prior -> direction gates  (+ weight transpose in block 0)
  p2w_k<<<(BB * LL) / 256, 256, 0, stream>>>(prior, alpha, w1, b1, bnw, bnb, bnm,
                                             bnv, w2, b2, xpw, xpwT, Wgb);
  // 3) fused dwconv+SiLU + x_proj(scan-order) + transpose  (32-px tiles, 1024 blocks)
  convproj_k<<<dim3(128, BB), 256, 0, stream>>>(xz, cw, cb, xpwT, xcT, projS);
  // 4) scan: segment carries
  scan_part_k<<<dim3(SS, KK, BB), 192, 0, stream>>>(xcT, projS, dtw, dtb, A_logs,
                                                    carrP, carrH);
  // 5) scan: serial carry combine
  scan_fix_k<<<dim3(KK, BB), 192, 0, stream>>>(carrP, carrH, h0b);
  // 6) scan: apply + gate + paired merge (ymT overlaid on xz x_ssm half)
  scan_apply_k<<<dim3(SS, 2, BB), 192, 0, stream>>>(xcT, projS, Wgb, h0b, dtw, dtb,
                                                    A_logs, Ds, ymT, ymT2);
  // 7) LayerNorm(channel) * silu(z)
  ln_silu_k<<<dim3(HH, BB), 256, 0, stream>>>(ymT, ymT2, xz, onw, onb, u);
  // 8) out_proj GEMM
  gemm_pix_k<DIN><<<dim3(LL / 1024, COUT / 8, BB), 256, 0, stream>>>(u, opw, out, COUT);
}